// Round 12
// baseline (963.420 us; speedup 1.0000x reference)
//
#include <hip/hip_runtime.h>
#include <cstdint>
#include <cstddef>

#define SEQ 5000
#define CIN 12
#define KL 9
#define ND 10
#define KPD 1000
#define NB 16
#define KPAD 128              // padded taps (108 -> 128)
#define NKP 1024              // padded kernels per dilation
#define BM 64                 // t-rows per strip
#define SPB 79                // strips per batch = ceil(5000/64)
#define STRIP_US (BM * KPAD)  // 8192 ushorts = 16KB per strip
#define QS 20                 // strips per quarter (last quarter: 19)

typedef __attribute__((ext_vector_type(4))) float f32x4;
typedef __attribute__((ext_vector_type(8))) __bf16 bf16x8;
typedef __attribute__((ext_vector_type(8))) unsigned short u16x8;

__device__ __forceinline__ unsigned fkey(float f) {
    unsigned u = __float_as_uint(f);
    return (u & 0x80000000u) ? ~u : (u | 0x80000000u);
}
__device__ __forceinline__ float unfkey(unsigned k) {
    unsigned u = (k & 0x80000000u) ? (k ^ 0x80000000u) : ~k;
    return __uint_as_float(u);
}
__device__ __forceinline__ unsigned short f2bf(float f) {
    unsigned u = __float_as_uint(f);
    u += 0x7fffu + ((u >> 16) & 1u);
    return (unsigned short)(u >> 16);
}

// ---- weight prep: [10][1000][108] f32 -> [10][1024][128] bf16, zero-padded ----
__global__ __launch_bounds__(256) void wprep(const float* __restrict__ w,
                                             unsigned short* __restrict__ wbf) {
    const int i = blockIdx.x * 256 + threadIdx.x;
    if (i >= ND * NKP * KPAD) return;
    const int kk   = i & (KPAD - 1);
    const int krow = (i >> 7) & (NKP - 1);
    const int di   = i >> 17;
    float v = 0.f;
    if (krow < KPD && kk < CIN * KL)
        v = w[((size_t)di * KPD + krow) * (CIN * KL) + kk];
    wbf[i] = f2bf(v);
}

// ---- im2col v2: lane = t (coalesced x reads), LDS transpose, linear writeout.
// Strip layout (PRE-SWIZZLED, must match mr_gemm's ds_read):
//   ushort addr = row*KPAD + ((cw*8) ^ ((row&7)<<3)) for 8-tap chunk cw.
__global__ __launch_bounds__(256) void im2col(const float* __restrict__ x,
                                              unsigned short* __restrict__ Aim,
                                              int g0) {
    const int s  = blockIdx.x;
    const int b  = blockIdx.y;
    const int dl = blockIdx.z;
    const int d  = 1 << (g0 + dl);
    const int tid  = threadIdx.x;
    const int lane = tid & 63;
    const int wv   = tid >> 6;

    __shared__ __align__(16) unsigned short sb[STRIP_US];

    const float* xb = x + (size_t)b * CIN * SEQ;
    const int t0 = s * BM;
    const int t  = t0 + lane;            // this lane's output row
    const int base = t - 4 * d;          // SAME padding: pad_lo = 4d
    const bool rowvalid = (t < SEQ);

#pragma unroll
    for (int cwi = 0; cwi < 4; ++cwi) {
        const int cw = wv * 4 + cwi;
        u16x8 pk;
        int cc = cw * 8;
        int c = cc / 9, j = cc - c * 9;
#pragma unroll
        for (int e = 0; e < 8; ++e) {
            const int idx = base + j * d;
            float v = 0.f;
            if (rowvalid && cc < CIN * KL && idx >= 0 && idx < SEQ)
                v = xb[c * SEQ + idx];
            pk[e] = f2bf(v);
            ++cc; if (++j == KL) { j = 0; ++c; }
        }
        *(u16x8*)(sb + lane * KPAD + ((cw * 8) ^ ((lane & 7) << 3))) = pk;
    }
    __syncthreads();

    // linear coalesced writeout: 256 threads x 16B x 4 iters = 16KB
    unsigned short* outp = Aim + ((size_t)(dl * NB + b) * SPB + s) * STRIP_US;
#pragma unroll
    for (int i = 0; i < 4; ++i) {
        const int u = (i * 256 + tid) * 8;
        *(u16x8*)(outp + u) = *(const u16x8*)(sb + u);
    }
}

// ---- main GEMM-reduce: block = (ksub of 256 kernels, dl, batch, quarter) ----
// n=4 columns per wave: each A-frag ds_read feeds FOUR MFMAs (r11 was 2) ->
// LDS-pipe cycles/CU halve below the MFMA floor (r11 was LDS-read-bound).
__global__ __launch_bounds__(256, 4) void mr_gemm(
    const unsigned short* __restrict__ Aim,
    const unsigned short* __restrict__ wbf,
    const float* __restrict__ bias,
    unsigned* __restrict__ gkey, unsigned* __restrict__ gcnt,
    int g0, int nrest)
{
    __shared__ __align__(16) unsigned short lA[2][STRIP_US];  // 32KB dbuf

    // XCD co-location: the 4 ksub-siblings of one (dl,b,q) sit at phys strides
    // of nrest (= ng*64, always %8==0) -> same phys%8 -> same XCD L2.
    const int phys = blockIdx.x;
    const int ksub = phys / nrest;
    const int rest = phys - ksub * nrest;
    const int q  = rest & 3;
    const int b  = (rest >> 2) & 15;
    const int dl = rest >> 6;
    const int di = g0 + dl;

    const int tid  = threadIdx.x;
    const int lane = tid & 63;
    const int wv   = tid >> 6;
    const int fr   = lane & 15;
    const int ks   = lane >> 4;

    const int sBeg = q * QS;
    const int sEnd = (q == 3) ? SPB : (sBeg + QS);

    const unsigned short* Ab = Aim + (size_t)(dl * NB + b) * SPB * STRIP_US;
    const unsigned short* wd = wbf + (size_t)di * NKP * KPAD;
    const int kcb = ksub * 256 + wv * 64 + fr;          // wave's col base
    const unsigned short* wp = wd + (size_t)kcb * KPAD + ks * 8;
    const float* bb = bias + (size_t)di * KPD;

    float bv[4];
#pragma unroll
    for (int n = 0; n < 4; ++n) {
        const int kc = kcb + n * 16;
        bv[n] = (kc < KPD) ? bb[kc] : 3.0e38f;
    }

    // B fragments (loop-invariant; allocator may remat from global per strip —
    // L2-hot and overlapped, observed fine at r11's VGPR=48)
    bf16x8 bfr[4][4];
#pragma unroll
    for (int n = 0; n < 4; ++n)
#pragma unroll
        for (int kk = 0; kk < 4; ++kk)
            bfr[n][kk] = *(const bf16x8*)(wp + (size_t)(n * 16) * KPAD + kk * 32);

    float rmax[4];
    unsigned rcnt[4];
#pragma unroll
    for (int n = 0; n < 4; ++n) { rmax[n] = -3.0e38f; rcnt[n] = 0; }

    // swizzled A-frag base byte addrs (bit7 clear -> +128 folds as imm)
    int abase[4];
#pragma unroll
    for (int m = 0; m < 4; ++m) {
        const int row = m * 16 + fr;
        abase[m] = row * 256 + ((ks * 16) ^ ((row & 7) << 4));
    }

    // prologue: stage strip sBeg into buf0 (linear dest, lane*16 implicit)
    {
        const char* src = (const char*)(Ab + (size_t)sBeg * STRIP_US) + wv * 4096 + lane * 16;
        char* dst = (char*)&lA[0][0] + wv * 4096;
#pragma unroll
        for (int i = 0; i < 4; ++i)
            __builtin_amdgcn_global_load_lds(
                (const __attribute__((address_space(1))) unsigned int*)(src + i * 1024),
                (__attribute__((address_space(3))) unsigned int*)(dst + i * 1024),
                16, 0, 0);
    }
    __syncthreads();

    for (int s = sBeg; s < sEnd; ++s) {
        const int cur = (s - sBeg) & 1;
        if (s + 1 < sEnd) {   // stage next strip into other buffer
            const char* src = (const char*)(Ab + (size_t)(s + 1) * STRIP_US) + wv * 4096 + lane * 16;
            char* dst = (char*)&lA[cur ^ 1][0] + wv * 4096;
#pragma unroll
            for (int i = 0; i < 4; ++i)
                __builtin_amdgcn_global_load_lds(
                    (const __attribute__((address_space(1))) unsigned int*)(src + i * 1024),
                    (__attribute__((address_space(3))) unsigned int*)(dst + i * 1024),
                    16, 0, 0);
        }

        const char* bufc = (const char*)&lA[cur][0];
        f32x4 acc[4][4];
#pragma unroll
        for (int m = 0; m < 4; ++m)
#pragma unroll
            for (int n = 0; n < 4; ++n)
                acc[m][n] = (f32x4){0.f, 0.f, 0.f, 0.f};

        // each A-frag read once, feeds FOUR MFMAs (0.25 ds_read/MFMA)
#pragma unroll
        for (int m = 0; m < 4; ++m) {
            const char* pa0 = bufc + abase[m];
            const char* pa1 = bufc + (abase[m] ^ 64);
#pragma unroll
            for (int kk = 0; kk < 4; ++kk) {
                const char* p = (kk & 1) ? pa1 : pa0;
                const bf16x8 a = *(const bf16x8*)(p + (kk >> 1) * 128);
#pragma unroll
                for (int n = 0; n < 4; ++n)
                    acc[m][n] = __builtin_amdgcn_mfma_f32_16x16x32_bf16(
                        a, bfr[n][kk], acc[m][n], 0, 0, 0);
            }
        }

        // per-lane running stats: NO shuffles / atomics per strip
        if (s != SPB - 1) {
#pragma unroll
            for (int n = 0; n < 4; ++n) {
                float m0 = -3.0e38f;
                unsigned c0 = 0;
#pragma unroll
                for (int m = 0; m < 4; ++m) {
#pragma unroll
                    for (int r = 0; r < 4; ++r) {
                        const float x0 = acc[m][n][r];
                        m0 = fmaxf(m0, x0);
                        c0 += (x0 > bv[n]) ? 1u : 0u;
                    }
                }
                rmax[n] = fmaxf(rmax[n], m0);
                rcnt[n] += c0;
            }
        } else {
            // tail strip 78: rows 4992..5055, valid t<5000 -> rows 0..7 only
            if (ks < 2) {
#pragma unroll
                for (int n = 0; n < 4; ++n) {
#pragma unroll
                    for (int r = 0; r < 4; ++r) {
                        const float x0 = acc[0][n][r];
                        rmax[n] = fmaxf(rmax[n], x0);
                        rcnt[n] += (x0 > bv[n]) ? 1u : 0u;
                    }
                }
            }
        }
        __syncthreads();   // reads of cur done + stage of cur^1 landed
    }

    // ONE cross-lane reduce + atomic set per block (amortized over ~20 strips)
#pragma unroll
    for (int n = 0; n < 4; ++n) {
        rmax[n] = fmaxf(rmax[n], __shfl_xor(rmax[n], 16, 64));
        rcnt[n] += (unsigned)__shfl_xor((int)rcnt[n], 16, 64);
        rmax[n] = fmaxf(rmax[n], __shfl_xor(rmax[n], 32, 64));
        rcnt[n] += (unsigned)__shfl_xor((int)rcnt[n], 32, 64);
    }

    if (lane < 16) {
        const size_t slotbase = ((size_t)b * ND + di) * KPD;
#pragma unroll
        for (int n = 0; n < 4; ++n) {
            const int kc = kcb + n * 16;
            if (kc < KPD) {
                atomicMax(&gkey[slotbase + kc], fkey(rmax[n]));
                atomicAdd(&gcnt[slotbase + kc], rcnt[n]);
            }
        }
    }
}

__global__ __launch_bounds__(256) void mr_fin(
    const unsigned* __restrict__ gkey, const unsigned* __restrict__ gcnt,
    float* __restrict__ out)
{
    const int i = blockIdx.x * 256 + threadIdx.x;   // over NB*ND*KPD
    if (i >= NB * ND * KPD) return;
    const int k  = i % KPD;
    const int di = (i / KPD) % ND;
    const int b  = i / (KPD * ND);
    const float maxv = unfkey(gkey[i]);
    const float ppv  = (float)gcnt[i] * (1.0f / (float)SEQ);
    float* ob = out + (size_t)b * (2 * ND * KPD);
    ob[di * 2 * KPD + k]       = maxv;
    ob[di * 2 * KPD + KPD + k] = ppv;
}

extern "C" void kernel_launch(void* const* d_in, const int* in_sizes, int n_in,
                              void* d_out, int out_size, void* d_ws, size_t ws_size,
                              hipStream_t stream) {
    const float* x    = (const float*)d_in[0];
    const float* w    = (const float*)d_in[1];
    const float* bias = (const float*)d_in[2];
    float* out = (float*)d_out;

    const size_t statsB = (size_t)NB * ND * KPD * 4;        // 640,000 B
    const size_t wbfB   = (size_t)ND * NKP * KPAD * 2;      // 2,621,440 B
    unsigned* gkey = (unsigned*)d_ws;
    unsigned* gcnt = (unsigned*)((char*)d_ws + statsB);
    unsigned short* wbf = (unsigned short*)((char*)d_ws + 2 * statsB);
    unsigned short* Aim = (unsigned short*)((char*)d_ws + 2 * statsB + wbfB);

    // group dilations to fit Aim in the available workspace
    const size_t perDil = (size_t)NB * SPB * STRIP_US * 2;  // 20,709,376 B
    const size_t head = 2 * statsB + wbfB;
    size_t avail = (ws_size > head) ? (ws_size - head) : 0;
    int NG = (int)(avail / perDil);
    if (NG > ND) NG = ND;
    if (NG < 1) NG = 1;

    hipMemsetAsync(d_ws, 0, 2 * statsB, stream);

    const int wtot = ND * NKP * KPAD;
    wprep<<<(wtot + 255) / 256, 256, 0, stream>>>(w, wbf);

    for (int g0 = 0; g0 < ND; g0 += NG) {
        const int ng = (ND - g0 < NG) ? (ND - g0) : NG;
        im2col<<<dim3(SPB, NB, ng), 256, 0, stream>>>(x, Aim, g0);
        const int nrest = ng * 64;                 // always %8==0
        mr_gemm<<<4 * nrest, 256, 0, stream>>>(Aim, wbf, bias, gkey, gcnt, g0, nrest);
    }

    const int tot = NB * ND * KPD;
    mr_fin<<<(tot + 255) / 256, 256, 0, stream>>>(gkey, gcnt, out);
}

// Round 14
// 276.492 us; speedup vs baseline: 3.4844x; 3.4844x over previous
//
#include <hip/hip_runtime.h>
#include <cstdint>
#include <cstddef>

#define SEQ 5000
#define CIN 12
#define KL 9
#define ND 10
#define KPD 1000
#define NB 16
#define KPAD 128              // padded taps (108 -> 128)
#define NKP 1024              // padded kernels per dilation
#define BM 64                 // t-rows per strip
#define SPB 79                // strips per batch = ceil(5000/64)
#define STRIP_US (BM * KPAD)  // 8192 ushorts = 16KB per strip
#define QS 20                 // strips per quarter (last quarter: 19)

typedef __attribute__((ext_vector_type(4))) float f32x4;
typedef __attribute__((ext_vector_type(8))) __bf16 bf16x8;
typedef __attribute__((ext_vector_type(8))) unsigned short u16x8;

__device__ __forceinline__ unsigned fkey(float f) {
    unsigned u = __float_as_uint(f);
    return (u & 0x80000000u) ? ~u : (u | 0x80000000u);
}
__device__ __forceinline__ float unfkey(unsigned k) {
    unsigned u = (k & 0x80000000u) ? (k ^ 0x80000000u) : ~k;
    return __uint_as_float(u);
}
__device__ __forceinline__ unsigned short f2bf(float f) {
    unsigned u = __float_as_uint(f);
    u += 0x7fffu + ((u >> 16) & 1u);
    return (unsigned short)(u >> 16);
}

// ---- weight prep: [10][1000][108] f32 -> [10][1024][128] bf16, zero-padded ----
__global__ __launch_bounds__(256) void wprep(const float* __restrict__ w,
                                             unsigned short* __restrict__ wbf) {
    const int i = blockIdx.x * 256 + threadIdx.x;
    if (i >= ND * NKP * KPAD) return;
    const int kk   = i & (KPAD - 1);
    const int krow = (i >> 7) & (NKP - 1);
    const int di   = i >> 17;
    float v = 0.f;
    if (krow < KPD && kk < CIN * KL)
        v = w[((size_t)di * KPD + krow) * (CIN * KL) + kk];
    wbf[i] = f2bf(v);
}

// ---- im2col v2: lane = t (coalesced x reads), LDS transpose, linear writeout.
// Strip layout (PRE-SWIZZLED, must match mr_gemm's ds_read):
//   ushort addr = row*KPAD + ((cw*8) ^ ((row&7)<<3)) for 8-tap chunk cw.
__global__ __launch_bounds__(256) void im2col(const float* __restrict__ x,
                                              unsigned short* __restrict__ Aim,
                                              int g0) {
    const int s  = blockIdx.x;
    const int b  = blockIdx.y;
    const int dl = blockIdx.z;
    const int d  = 1 << (g0 + dl);
    const int tid  = threadIdx.x;
    const int lane = tid & 63;
    const int wv   = tid >> 6;

    __shared__ __align__(16) unsigned short sb[STRIP_US];

    const float* xb = x + (size_t)b * CIN * SEQ;
    const int t0 = s * BM;
    const int t  = t0 + lane;            // this lane's output row
    const int base = t - 4 * d;          // SAME padding: pad_lo = 4d
    const bool rowvalid = (t < SEQ);

#pragma unroll
    for (int cwi = 0; cwi < 4; ++cwi) {
        const int cw = wv * 4 + cwi;
        u16x8 pk;
        int cc = cw * 8;
        int c = cc / 9, j = cc - c * 9;
#pragma unroll
        for (int e = 0; e < 8; ++e) {
            const int idx = base + j * d;
            float v = 0.f;
            if (rowvalid && cc < CIN * KL && idx >= 0 && idx < SEQ)
                v = xb[c * SEQ + idx];
            pk[e] = f2bf(v);
            ++cc; if (++j == KL) { j = 0; ++c; }
        }
        *(u16x8*)(sb + lane * KPAD + ((cw * 8) ^ ((lane & 7) << 3))) = pk;
    }
    __syncthreads();

    // linear coalesced writeout: 256 threads x 16B x 4 iters = 16KB
    unsigned short* outp = Aim + ((size_t)(dl * NB + b) * SPB + s) * STRIP_US;
#pragma unroll
    for (int i = 0; i < 4; ++i) {
        const int u = (i * 256 + tid) * 8;
        *(u16x8*)(outp + u) = *(const u16x8*)(sb + u);
    }
}

// ---- main GEMM-reduce: block = 64 rows x 128 kernels; waves split 2Mx2N ----
// Each wave: 32 rows x 64 kernels -> A ds_reads 8/strip (r11: 16), MFMA 32,
// B 64 regs held across the loop (unified pressure ~126 <= 128 budget).
__global__ __launch_bounds__(256, 4) void mr_gemm(
    const unsigned short* __restrict__ Aim,
    const unsigned short* __restrict__ wbf,
    const float* __restrict__ bias,
    unsigned* __restrict__ gkey, unsigned* __restrict__ gcnt, int g0)
{
    __shared__ __align__(16) unsigned short lA[2][STRIP_US];  // 32KB dbuf

    // XCD co-location (identical to r11): siblings (same gg, diff ksub) share
    // phys%8 -> same XCD L2 caches their common A-slice.
    const int phys = blockIdx.x;
    const int gg   = ((phys >> 6) << 3) | (phys & 7);
    const int ksub = (phys >> 3) & 7;
    const int q  = gg & 3;
    const int b  = (gg >> 2) & 15;
    const int dl = gg >> 6;
    const int di = g0 + dl;

    const int tid  = threadIdx.x;
    const int lane = tid & 63;
    const int wv   = tid >> 6;
    const int wm   = wv >> 1;        // row half: rows wm*32 .. wm*32+31
    const int wn   = wv & 1;         // col half: kernels wn*64 .. wn*64+63
    const int fr   = lane & 15;
    const int ks   = lane >> 4;

    const int sBeg = q * QS;
    const int sEnd = (q == 3) ? SPB : (sBeg + QS);

    const unsigned short* Ab = Aim + (size_t)(dl * NB + b) * SPB * STRIP_US;
    const unsigned short* wd = wbf + (size_t)di * NKP * KPAD;
    const int kcb = ksub * 128 + wn * 64 + fr;     // lane's kernel for n=0
    const unsigned short* wp = wd + (size_t)kcb * KPAD + ks * 8;
    const float* bb = bias + (size_t)di * KPD;

    float bv[4];
#pragma unroll
    for (int n = 0; n < 4; ++n) {
        const int kc = kcb + n * 16;
        bv[n] = (kc < KPD) ? bb[kc] : 3.0e38f;
    }

    // B fragments: 16 x bf16x8 = 64 regs, loaded ONCE, live across the loop
    bf16x8 bfr[4][4];
#pragma unroll
    for (int n = 0; n < 4; ++n)
#pragma unroll
        for (int kk = 0; kk < 4; ++kk)
            bfr[n][kk] = *(const bf16x8*)(wp + (size_t)(n * 16) * KPAD + kk * 32);

    float rmax[4];
    unsigned rcnt[4];
#pragma unroll
    for (int n = 0; n < 4; ++n) { rmax[n] = -3.0e38f; rcnt[n] = 0; }

    // swizzled A-frag base byte addrs for this wave's two 16-row strips
    int abase[2];
#pragma unroll
    for (int m2 = 0; m2 < 2; ++m2) {
        const int row = wm * 32 + m2 * 16 + fr;
        abase[m2] = row * 256 + ((ks * 16) ^ ((row & 7) << 4));
    }

    // prologue: stage strip sBeg into buf0 (linear dest, lane*16 implicit)
    {
        const char* src = (const char*)(Ab + (size_t)sBeg * STRIP_US) + wv * 4096 + lane * 16;
        char* dst = (char*)&lA[0][0] + wv * 4096;
#pragma unroll
        for (int i = 0; i < 4; ++i)
            __builtin_amdgcn_global_load_lds(
                (const __attribute__((address_space(1))) unsigned int*)(src + i * 1024),
                (__attribute__((address_space(3))) unsigned int*)(dst + i * 1024),
                16, 0, 0);
    }
    __syncthreads();

    for (int s = sBeg; s < sEnd; ++s) {
        const int cur = (s - sBeg) & 1;
        if (s + 1 < sEnd) {   // stage next strip into other buffer
            const char* src = (const char*)(Ab + (size_t)(s + 1) * STRIP_US) + wv * 4096 + lane * 16;
            char* dst = (char*)&lA[cur ^ 1][0] + wv * 4096;
#pragma unroll
            for (int i = 0; i < 4; ++i)
                __builtin_amdgcn_global_load_lds(
                    (const __attribute__((address_space(1))) unsigned int*)(src + i * 1024),
                    (__attribute__((address_space(3))) unsigned int*)(dst + i * 1024),
                    16, 0, 0);
        }

        const char* bufc = (const char*)&lA[cur][0];
        f32x4 acc[2][4];
#pragma unroll
        for (int m2 = 0; m2 < 2; ++m2)
#pragma unroll
            for (int n = 0; n < 4; ++n)
                acc[m2][n] = (f32x4){0.f, 0.f, 0.f, 0.f};

        // each A-frag read once, feeds FOUR MFMAs (8 ds_read / 32 MFMA)
#pragma unroll
        for (int m2 = 0; m2 < 2; ++m2) {
            const char* pa0 = bufc + abase[m2];
            const char* pa1 = bufc + (abase[m2] ^ 64);
#pragma unroll
            for (int kk = 0; kk < 4; ++kk) {
                const char* p = (kk & 1) ? pa1 : pa0;
                const bf16x8 a = *(const bf16x8*)(p + (kk >> 1) * 128);
#pragma unroll
                for (int n = 0; n < 4; ++n)
                    acc[m2][n] = __builtin_amdgcn_mfma_f32_16x16x32_bf16(
                        a, bfr[n][kk], acc[m2][n], 0, 0, 0);
            }
        }

        // per-lane running stats: NO shuffles / atomics per strip
        if (s != SPB - 1) {
#pragma unroll
            for (int n = 0; n < 4; ++n) {
                float m0 = -3.0e38f;
                unsigned c0 = 0;
#pragma unroll
                for (int m2 = 0; m2 < 2; ++m2) {
#pragma unroll
                    for (int r = 0; r < 4; ++r) {
                        const float x0 = acc[m2][n][r];
                        m0 = fmaxf(m0, x0);
                        c0 += (x0 > bv[n]) ? 1u : 0u;
                    }
                }
                rmax[n] = fmaxf(rmax[n], m0);
                rcnt[n] += c0;
            }
        } else {
            // tail strip 78: valid t<5000 -> rows 0..7 (wm=0, m2=0, ks<2)
            if (wm == 0 && ks < 2) {
#pragma unroll
                for (int n = 0; n < 4; ++n) {
#pragma unroll
                    for (int r = 0; r < 4; ++r) {
                        const float x0 = acc[0][n][r];
                        rmax[n] = fmaxf(rmax[n], x0);
                        rcnt[n] += (x0 > bv[n]) ? 1u : 0u;
                    }
                }
            }
        }
        __syncthreads();   // reads of cur done + stage of cur^1 landed
    }

    // ONE cross-lane reduce + atomic set per wave (both wm waves merge via
    // atomics into the same slots)
#pragma unroll
    for (int n = 0; n < 4; ++n) {
        rmax[n] = fmaxf(rmax[n], __shfl_xor(rmax[n], 16, 64));
        rcnt[n] += (unsigned)__shfl_xor((int)rcnt[n], 16, 64);
        rmax[n] = fmaxf(rmax[n], __shfl_xor(rmax[n], 32, 64));
        rcnt[n] += (unsigned)__shfl_xor((int)rcnt[n], 32, 64);
    }

    if (lane < 16) {
        const size_t slotbase = ((size_t)b * ND + di) * KPD;
#pragma unroll
        for (int n = 0; n < 4; ++n) {
            const int kc = kcb + n * 16;   // kcb includes fr
            if (kc < KPD) {
                atomicMax(&gkey[slotbase + kc], fkey(rmax[n]));
                atomicAdd(&gcnt[slotbase + kc], rcnt[n]);
            }
        }
    }
}

__global__ __launch_bounds__(256) void mr_fin(
    const unsigned* __restrict__ gkey, const unsigned* __restrict__ gcnt,
    float* __restrict__ out)
{
    const int i = blockIdx.x * 256 + threadIdx.x;   // over NB*ND*KPD
    if (i >= NB * ND * KPD) return;
    const int k  = i % KPD;
    const int di = (i / KPD) % ND;
    const int b  = i / (KPD * ND);
    const float maxv = unfkey(gkey[i]);
    const float ppv  = (float)gcnt[i] * (1.0f / (float)SEQ);
    float* ob = out + (size_t)b * (2 * ND * KPD);
    ob[di * 2 * KPD + k]       = maxv;
    ob[di * 2 * KPD + KPD + k] = ppv;
}

extern "C" void kernel_launch(void* const* d_in, const int* in_sizes, int n_in,
                              void* d_out, int out_size, void* d_ws, size_t ws_size,
                              hipStream_t stream) {
    const float* x    = (const float*)d_in[0];
    const float* w    = (const float*)d_in[1];
    const float* bias = (const float*)d_in[2];
    float* out = (float*)d_out;

    const size_t statsB = (size_t)NB * ND * KPD * 4;        // 640,000 B
    const size_t wbfB   = (size_t)ND * NKP * KPAD * 2;      // 2,621,440 B
    unsigned* gkey = (unsigned*)d_ws;
    unsigned* gcnt = (unsigned*)((char*)d_ws + statsB);
    unsigned short* wbf = (unsigned short*)((char*)d_ws + 2 * statsB);
    unsigned short* Aim = (unsigned short*)((char*)d_ws + 2 * statsB + wbfB);

    // group dilations to fit Aim in the available workspace
    const size_t perDil = (size_t)NB * SPB * STRIP_US * 2;  // 20,709,376 B
    const size_t head = 2 * statsB + wbfB;
    size_t avail = (ws_size > head) ? (ws_size - head) : 0;
    int NG = (int)(avail / perDil);
    if (NG > ND) NG = ND;
    if (NG < 1) NG = 1;

    hipMemsetAsync(d_ws, 0, 2 * statsB, stream);

    const int wtot = ND * NKP * KPAD;
    wprep<<<(wtot + 255) / 256, 256, 0, stream>>>(w, wbf);

    for (int g0 = 0; g0 < ND; g0 += NG) {
        const int ng = (ND - g0 < NG) ? (ND - g0) : NG;
        im2col<<<dim3(SPB, NB, ng), 256, 0, stream>>>(x, Aim, g0);
        mr_gemm<<<ng * 512, 256, 0, stream>>>(Aim, wbf, bias, gkey, gcnt, g0);
    }

    const int tot = NB * ND * KPD;
    mr_fin<<<(tot + 255) / 256, 256, 0, stream>>>(gkey, gcnt, out);
}